// Round 2
// baseline (275.767 us; speedup 1.0000x reference)
//
#include <hip/hip_runtime.h>

// RecformerPooler: grouped nanmean over (attr, item) pairs.
// hidden [64,1024,768] f32, attr/item ids [64,1024] i32 -> out [64,3,32,768] f32.
//
// Gather design: one block per (batch, attr, item) output segment (6144 blocks).
//  Phase 1: int4-scan this batch's 1024 ids, collect matching token indices
//           into LDS (order-free via LDS atomic counter). ~8 KB ids, L2-hot.
//  Phase 2: threads 0..191 each own one float4 column of H=768; gather-sum the
//           ~8 matching 3 KB rows with 8 independent loads in flight per
//           thread (idx batch-read from LDS first, then 8 back-to-back
//           global_load_dwordx4 -> ~8 KB/wave outstanding, hides ~900cy HBM).
//  cnt==0 -> 0/0 -> NaN, exactly matching torch/jax nanmean on empty group.
// Every valid hidden row is read exactly once grid-wide; invalid rows never.
// Disjoint row sets per block -> no inter-block reuse -> no swizzle needed.

#define ATTR_N 3
#define ITEM_N 32
#define SEGS (ATTR_N * ITEM_N)   // 96
#define B_DIM 64
#define L_DIM 1024
#define H_DIM 768
#define PIPE 8                   // gather loads kept in flight per thread

__global__ __launch_bounds__(256) void recformer_pool_kernel(
    const float* __restrict__ hidden,
    const int*   __restrict__ attr,
    const int*   __restrict__ item,
    float*       __restrict__ out)
{
    __shared__ int match_idx[L_DIM];   // 4 KB
    __shared__ int match_cnt;

    const int blk = blockIdx.x;            // [0, 64*96)
    const int b   = blk / SEGS;
    const int seg = blk - b * SEGS;
    const int ta  = seg / ITEM_N + 1;      // target attr id (1..3)
    const int ti  = (seg & (ITEM_N - 1)) + 1;  // target item id (1..32)
    const int tid = threadIdx.x;

    if (tid == 0) match_cnt = 0;
    __syncthreads();

    // ---- Phase 1: scan ids, collect matching token indices ----
    {
        const int4 av = ((const int4*)(attr + b * L_DIM))[tid];  // 256*4 = 1024
        const int4 iv = ((const int4*)(item + b * L_DIM))[tid];
        const int l0 = tid * 4;
        if (av.x == ta && iv.x == ti) match_idx[atomicAdd(&match_cnt, 1)] = l0;
        if (av.y == ta && iv.y == ti) match_idx[atomicAdd(&match_cnt, 1)] = l0 + 1;
        if (av.z == ta && iv.z == ti) match_idx[atomicAdd(&match_cnt, 1)] = l0 + 2;
        if (av.w == ta && iv.w == ti) match_idx[atomicAdd(&match_cnt, 1)] = l0 + 3;
    }
    __syncthreads();
    const int cnt = match_cnt;

    // ---- Phase 2: gather-sum matching rows, 8 loads in flight ----
    if (tid < (H_DIM / 4)) {               // 192 threads x float4 = 768 floats
        const float* base = hidden + (size_t)b * (L_DIM * H_DIM) + tid * 4;
        float4 acc = make_float4(0.f, 0.f, 0.f, 0.f);

        int k = 0;
        while (k < cnt) {                  // wave-uniform loop
            const int take = (cnt - k >= PIPE) ? PIPE : (cnt - k);
            int idx[PIPE];                 // statically indexed (full unroll)
            #pragma unroll
            for (int j = 0; j < PIPE; ++j)
                idx[j] = (j < take) ? match_idx[k + j] : 0;
            float4 v[PIPE];
            #pragma unroll
            for (int j = 0; j < PIPE; ++j)
                if (j < take) v[j] = *(const float4*)(base + (size_t)idx[j] * H_DIM);
            #pragma unroll
            for (int j = 0; j < PIPE; ++j)
                if (j < take) {
                    acc.x += v[j].x; acc.y += v[j].y;
                    acc.z += v[j].z; acc.w += v[j].w;
                }
            k += take;
        }

        const float c = (float)cnt;        // cnt==0 -> 0/0 -> NaN (== nanmean)
        float4 r;
        r.x = acc.x / c; r.y = acc.y / c; r.z = acc.z / c; r.w = acc.w / c;
        *(float4*)(out + (size_t)blk * H_DIM + tid * 4) = r;
    }
}

extern "C" void kernel_launch(void* const* d_in, const int* in_sizes, int n_in,
                              void* d_out, int out_size, void* d_ws, size_t ws_size,
                              hipStream_t stream) {
    // setup_inputs order: [0] attention_mask (unused), [1] hidden_states,
    //                     [2] attr_type_ids, [3] item_position_ids
    const float* hidden = (const float*)d_in[1];
    const int*   attr   = (const int*)d_in[2];
    const int*   item   = (const int*)d_in[3];
    float*       out    = (float*)d_out;

    recformer_pool_kernel<<<dim3(B_DIM * SEGS), dim3(256), 0, stream>>>(
        hidden, attr, item, out);
}